// Round 13
// baseline (343.812 us; speedup 1.0000x reference)
//
#include <hip/hip_runtime.h>
#include <hip/hip_bf16.h>
#include <hip/hip_fp16.h>
#include <math.h>

typedef short short8 __attribute__((ext_vector_type(8)));
typedef _Float16 half8 __attribute__((ext_vector_type(8)));
typedef float f32x4  __attribute__((ext_vector_type(4)));

__device__ __forceinline__ unsigned short f2h(float f) {
    return __half_as_ushort(__float2half(f));
}
__device__ __forceinline__ float h2f(unsigned short u) {
    return __half2float(__ushort_as_half(u));
}

// ---------------- utility: fast zero ----------------

__global__ void k_zero(uint4* __restrict__ p, int n16) {
    int i = blockIdx.x * 256 + threadIdx.x;
    if (i < n16) p[i] = make_uint4(0u, 0u, 0u, 0u);
}

// ---------------- CSR build (rank-based, atomic-free scatter) -------------

__global__ void k_count(const int* __restrict__ dst, int* __restrict__ cnt,
                        unsigned short* __restrict__ rank, int E) {
    int e = blockIdx.x * 256 + threadIdx.x;
    if (e < E) rank[e] = (unsigned short)atomicAdd(&cnt[dst[e]], 1);
}

__global__ void k_scan_part(const int* __restrict__ cnt, int* __restrict__ offs,
                            int* __restrict__ parts, float* __restrict__ dinv, int n) {
    __shared__ int s[256];
    int i = blockIdx.x * 256 + threadIdx.x;
    int v = (i < n) ? cnt[i] : 0;
    s[threadIdx.x] = v;
    __syncthreads();
    #pragma unroll
    for (int d = 1; d < 256; d <<= 1) {
        int t = (threadIdx.x >= d) ? s[threadIdx.x - d] : 0;
        __syncthreads();
        s[threadIdx.x] += t;
        __syncthreads();
    }
    if (i < n) {
        offs[i] = s[threadIdx.x] - v;
        dinv[i] = rsqrtf((float)v + 1.0f);   // +1 self-loop
    }
    if (threadIdx.x == 255) parts[blockIdx.x] = s[255];
}

__global__ void k_scan_tops(int* __restrict__ parts, int np) {
    __shared__ int s[256];
    int tid = threadIdx.x;
    int v = (tid < np) ? parts[tid] : 0;
    s[tid] = v;
    __syncthreads();
    #pragma unroll
    for (int d = 1; d < 256; d <<= 1) {
        int t = (tid >= d) ? s[tid - d] : 0;
        __syncthreads();
        s[tid] += t;
        __syncthreads();
    }
    if (tid < np) parts[tid] = s[tid] - v;          // exclusive
}

__global__ void k_scan_add(int* __restrict__ offs, const int* __restrict__ parts,
                           int n, int e_total) {
    int i = blockIdx.x * 256 + threadIdx.x;
    if (i < n) offs[i] += parts[blockIdx.x];
    if (blockIdx.x == 0 && threadIdx.x == 0) offs[n] = e_total;
}

// csr entry (4B) = fp16(0.9*dinv[d]*dinv[s]) << 16 | src
__global__ void k_scatter(const int* __restrict__ dst, const int* __restrict__ src,
                          const unsigned short* __restrict__ rank,
                          const int* __restrict__ offs,
                          const float* __restrict__ dinv,
                          unsigned* __restrict__ csr, int E) {
    int e = blockIdx.x * 256 + threadIdx.x;
    if (e < E) {
        int d = dst[e], s = src[e];
        float w = 0.9f * dinv[d] * dinv[s];
        csr[offs[d] + (int)rank[e]] = ((unsigned)f2h(w) << 16) | (unsigned)s;
    }
}

// ---------------- weight prep (all fp16, transposed) ----------------

__global__ void k_wprep(const float* __restrict__ Wl, const float* __restrict__ Win,
                        const float* __restrict__ Wout,
                        unsigned short* __restrict__ wt,
                        unsigned short* __restrict__ wint,
                        unsigned short* __restrict__ wot, int C) {
    int m = blockIdx.x;
    if (m < 4) {
        for (int i = threadIdx.x; i < 16384; i += 256) {
            int n = i >> 7, k = i & 127;
            wt[m * 16384 + n * 128 + k] = f2h(Wl[m * 16384 + k * 128 + n]);
        }
    } else if (m == 4) {
        for (int i = threadIdx.x; i < 16384; i += 256) {
            int n = i >> 7, k = i & 127;
            wint[n * 128 + k] = f2h(Win[k * 128 + n]);
        }
    } else {
        for (int i = threadIdx.x; i < 48 * 128; i += 256) {
            int n = i >> 7, k = i & 127;
            wot[n * 128 + k] = (n < C) ? f2h(Wout[k * C + n]) : (unsigned short)0;
        }
    }
}

// ---------------- input GEMM: relu(x@W_in + b) -> hb, h0b (fp16) ----------

__global__ __launch_bounds__(256)
void gemm_in(const float* __restrict__ inA,
             const unsigned short* __restrict__ Bh,
             const float* __restrict__ bias,
             unsigned short* __restrict__ hb,
             unsigned short* __restrict__ h0b, int M) {
    extern __shared__ char lds[];
    char* Ah = lds;                  // 64*128 fp16 = 16KB
    char* Wh = Ah + 16384;           // 32KB

    const int tid  = threadIdx.x;
    const int row0 = blockIdx.x * 64;

    for (int c = tid; c < 1024; c += 256) {            // 64 rows x 16 chunks
        int row = c >> 4, k8 = c & 15;
        int grow = row0 + row;
        short8 hv = {0,0,0,0,0,0,0,0};
        if (grow < M) {
            const float* s = &inA[(size_t)grow * 128 + k8 * 8];
            float4 f0 = *(const float4*)s;
            float4 f1 = *(const float4*)(s + 4);
            float ff[8] = {f0.x, f0.y, f0.z, f0.w, f1.x, f1.y, f1.z, f1.w};
            #pragma unroll
            for (int j = 0; j < 8; ++j) hv[j] = (short)f2h(ff[j]);
        }
        *(short8*)(Ah + row * 256 + ((k8 ^ (row & 7)) << 4)) = hv;
    }
    for (int c = tid; c < 2048; c += 256) {
        int n = c >> 4, k8 = c & 15;
        *(short8*)(Wh + n * 256 + ((k8 ^ (n & 7)) << 4)) = *(const short8*)&Bh[n * 128 + k8 * 8];
    }
    __syncthreads();

    const int lane = tid & 63;
    const int w    = tid >> 6;
    const int lr   = lane & 15;
    const int lg   = lane >> 4;

    f32x4 acc[4][2];
    #pragma unroll
    for (int m = 0; m < 4; ++m)
        #pragma unroll
        for (int n2 = 0; n2 < 2; ++n2) acc[m][n2] = (f32x4){0.f, 0.f, 0.f, 0.f};

    #pragma unroll
    for (int kk = 0; kk < 4; ++kk) {
        int k8 = kk * 4 + lg;
        half8 a[4], b[2];
        #pragma unroll
        for (int m = 0; m < 4; ++m) {
            int row = m * 16 + lr;
            a[m] = *(const half8*)(Ah + row * 256 + ((k8 ^ (row & 7)) << 4));
        }
        #pragma unroll
        for (int n2 = 0; n2 < 2; ++n2) {
            int n = (w * 2 + n2) * 16 + lr;
            b[n2] = *(const half8*)(Wh + n * 256 + ((k8 ^ (n & 7)) << 4));
        }
        #pragma unroll
        for (int m = 0; m < 4; ++m)
            #pragma unroll
            for (int n2 = 0; n2 < 2; ++n2)
                acc[m][n2] = __builtin_amdgcn_mfma_f32_16x16x32_f16(a[m], b[n2], acc[m][n2], 0, 0, 0);
    }

    #pragma unroll
    for (int m = 0; m < 4; ++m) {
        #pragma unroll
        for (int n2 = 0; n2 < 2; ++n2) {
            int col = (w * 2 + n2) * 16 + lr;
            #pragma unroll
            for (int r = 0; r < 4; ++r) {
                int row = row0 + m * 16 + lg * 4 + r;
                if (row < M) {
                    float o = fmaxf(acc[m][n2][r] + bias[col], 0.f);
                    unsigned short ob = f2h(o);
                    hb [(size_t)row * 128 + col] = ob;
                    h0b[(size_t)row * 128 + col] = ob;
                }
            }
        }
    }
}

// ---------------- fused layer: SpMM gather -> LDS -> MFMA -----------------
// Phase 1: half-wave per node (8 nodes each), sup = 0.9*A_hat*hin + 0.1*h0
//          accumulated fp32, packed fp16 into the swizzled LDS A-tile.
// Phase 2: h = relu(beta*(sup@W) + gamma*sup) via f16 MFMA; residual read
//          from the LDS tile. !LAST: write hout (ping-pong). LAST: write h
//          back into LDS (owner-unique slots), swap W_out into Wh, second
//          MFMA -> out (fp32, [M,C]).

template<int LAST>
__global__ __launch_bounds__(256)
void k_layer(const int* __restrict__ offs, const unsigned* __restrict__ csr,
             const unsigned short* __restrict__ hin,
             const unsigned short* __restrict__ h0b,
             const float* __restrict__ dinv,
             const unsigned short* __restrict__ Bh,
             const unsigned short* __restrict__ Wot,
             const float* __restrict__ obias,
             float beta, float gamma,
             unsigned short* __restrict__ hout,
             float* __restrict__ outf,
             int M, int C, int E) {
    extern __shared__ char lds[];
    char* Ah = lds;                  // 64 rows x 256B = 16KB
    char* Wh = Ah + 16384;           // 32KB

    const int tid  = threadIdx.x;
    const int row0 = blockIdx.x * 64;

    // stage layer weight (issued before gathers; barrier below covers it)
    for (int c = tid; c < 2048; c += 256) {
        int n = c >> 4, k8 = c & 15;
        *(short8*)(Wh + n * 256 + ((k8 ^ (n & 7)) << 4)) = *(const short8*)&Bh[n * 128 + k8 * 8];
    }

    // ---- phase 1: SpMM gather ----
    const int hw  = tid >> 5;        // half-wave 0..7
    const int l32 = tid & 31;        // lane in half-wave; owns 4 features
    for (int it = 0; it < 8; ++it) {
        int li   = hw * 8 + it;      // local node 0..63
        int node = row0 + li;
        float ax = 0.f, ay = 0.f, az = 0.f, aw = 0.f;
        if (node < M) {
            float di = dinv[node];
            float ws = 0.9f * di * di;
            uint2 sv = *(const uint2*)&hin[((size_t)node << 7) + (l32 << 2)];
            uint2 rv = *(const uint2*)&h0b[((size_t)node << 7) + (l32 << 2)];
            ax = ws * h2f((unsigned short)(sv.x & 0xffffu)) + 0.1f * h2f((unsigned short)(rv.x & 0xffffu));
            ay = ws * h2f((unsigned short)(sv.x >> 16))     + 0.1f * h2f((unsigned short)(rv.x >> 16));
            az = ws * h2f((unsigned short)(sv.y & 0xffffu)) + 0.1f * h2f((unsigned short)(rv.y & 0xffffu));
            aw = ws * h2f((unsigned short)(sv.y >> 16))     + 0.1f * h2f((unsigned short)(rv.y >> 16));
            int e = offs[node], end = offs[node + 1];
            while (e < end) {
                int nb = end - e;
                if (nb > 32) nb = 32;
                unsigned ce = csr[min(e + l32, E - 1)];
                int i = 0;
                for (; i + 16 <= nb; i += 16) {
                    uint2 g[16]; float wv[16];
                    #pragma unroll
                    for (int j = 0; j < 16; ++j) {
                        unsigned u = __shfl(ce, i + j, 32);
                        wv[j] = h2f((unsigned short)(u >> 16));
                        g[j] = *(const uint2*)&hin[((size_t)(u & 0xffffu) << 7) + (l32 << 2)];
                    }
                    #pragma unroll
                    for (int j = 0; j < 16; ++j) {
                        ax += wv[j] * h2f((unsigned short)(g[j].x & 0xffffu));
                        ay += wv[j] * h2f((unsigned short)(g[j].x >> 16));
                        az += wv[j] * h2f((unsigned short)(g[j].y & 0xffffu));
                        aw += wv[j] * h2f((unsigned short)(g[j].y >> 16));
                    }
                }
                for (; i + 8 <= nb; i += 8) {
                    uint2 g[8]; float wv[8];
                    #pragma unroll
                    for (int j = 0; j < 8; ++j) {
                        unsigned u = __shfl(ce, i + j, 32);
                        wv[j] = h2f((unsigned short)(u >> 16));
                        g[j] = *(const uint2*)&hin[((size_t)(u & 0xffffu) << 7) + (l32 << 2)];
                    }
                    #pragma unroll
                    for (int j = 0; j < 8; ++j) {
                        ax += wv[j] * h2f((unsigned short)(g[j].x & 0xffffu));
                        ay += wv[j] * h2f((unsigned short)(g[j].x >> 16));
                        az += wv[j] * h2f((unsigned short)(g[j].y & 0xffffu));
                        aw += wv[j] * h2f((unsigned short)(g[j].y >> 16));
                    }
                }
                for (; i + 4 <= nb; i += 4) {
                    uint2 g[4]; float wv[4];
                    #pragma unroll
                    for (int j = 0; j < 4; ++j) {
                        unsigned u = __shfl(ce, i + j, 32);
                        wv[j] = h2f((unsigned short)(u >> 16));
                        g[j] = *(const uint2*)&hin[((size_t)(u & 0xffffu) << 7) + (l32 << 2)];
                    }
                    #pragma unroll
                    for (int j = 0; j < 4; ++j) {
                        ax += wv[j] * h2f((unsigned short)(g[j].x & 0xffffu));
                        ay += wv[j] * h2f((unsigned short)(g[j].x >> 16));
                        az += wv[j] * h2f((unsigned short)(g[j].y & 0xffffu));
                        aw += wv[j] * h2f((unsigned short)(g[j].y >> 16));
                    }
                }
                for (; i + 2 <= nb; i += 2) {
                    uint2 g[2]; float wv[2];
                    #pragma unroll
                    for (int j = 0; j < 2; ++j) {
                        unsigned u = __shfl(ce, i + j, 32);
                        wv[j] = h2f((unsigned short)(u >> 16));
                        g[j] = *(const uint2*)&hin[((size_t)(u & 0xffffu) << 7) + (l32 << 2)];
                    }
                    #pragma unroll
                    for (int j = 0; j < 2; ++j) {
                        ax += wv[j] * h2f((unsigned short)(g[j].x & 0xffffu));
                        ay += wv[j] * h2f((unsigned short)(g[j].x >> 16));
                        az += wv[j] * h2f((unsigned short)(g[j].y & 0xffffu));
                        aw += wv[j] * h2f((unsigned short)(g[j].y >> 16));
                    }
                }
                for (; i < nb; ++i) {
                    unsigned u = __shfl(ce, i, 32);
                    float w = h2f((unsigned short)(u >> 16));
                    uint2 g = *(const uint2*)&hin[((size_t)(u & 0xffffu) << 7) + (l32 << 2)];
                    ax += w * h2f((unsigned short)(g.x & 0xffffu));
                    ay += w * h2f((unsigned short)(g.x >> 16));
                    az += w * h2f((unsigned short)(g.y & 0xffffu));
                    aw += w * h2f((unsigned short)(g.y >> 16));
                }
                e += nb;
            }
        }
        // pack to fp16, write swizzled 8B chunk-half
        unsigned plo = (unsigned)f2h(ax) | ((unsigned)f2h(ay) << 16);
        unsigned phi = (unsigned)f2h(az) | ((unsigned)f2h(aw) << 16);
        int k8  = l32 >> 1;
        int off = li * 256 + ((k8 ^ (li & 7)) << 4) + (l32 & 1) * 8;
        *(uint2*)(Ah + off) = make_uint2(plo, phi);
    }
    __syncthreads();

    // ---- phase 2: MFMA ----
    const int lane = tid & 63;
    const int w    = tid >> 6;
    const int lr   = lane & 15;
    const int lg   = lane >> 4;

    f32x4 acc[4][2];
    #pragma unroll
    for (int m = 0; m < 4; ++m)
        #pragma unroll
        for (int n2 = 0; n2 < 2; ++n2) acc[m][n2] = (f32x4){0.f, 0.f, 0.f, 0.f};

    #pragma unroll
    for (int kk = 0; kk < 4; ++kk) {
        int k8 = kk * 4 + lg;
        half8 a[4], b[2];
        #pragma unroll
        for (int m = 0; m < 4; ++m) {
            int row = m * 16 + lr;
            a[m] = *(const half8*)(Ah + row * 256 + ((k8 ^ (row & 7)) << 4));
        }
        #pragma unroll
        for (int n2 = 0; n2 < 2; ++n2) {
            int n = (w * 2 + n2) * 16 + lr;
            b[n2] = *(const half8*)(Wh + n * 256 + ((k8 ^ (n & 7)) << 4));
        }
        #pragma unroll
        for (int m = 0; m < 4; ++m)
            #pragma unroll
            for (int n2 = 0; n2 < 2; ++n2)
                acc[m][n2] = __builtin_amdgcn_mfma_f32_16x16x32_f16(a[m], b[n2], acc[m][n2], 0, 0, 0);
    }

    // ---- epilogue: residual + relu ----
    #pragma unroll
    for (int m = 0; m < 4; ++m) {
        #pragma unroll
        for (int n2 = 0; n2 < 2; ++n2) {
            int col = (w * 2 + n2) * 16 + lr;
            int k8c = col >> 3;
            int ebc = (col & 7) * 2;
            #pragma unroll
            for (int r = 0; r < 4; ++r) {
                int rl  = m * 16 + lg * 4 + r;
                int row = row0 + rl;
                // each (rl,col) is owned by exactly this thread: safe to
                // read residual then overwrite in place (LAST).
                unsigned short rb = *(const unsigned short*)
                    (Ah + rl * 256 + ((k8c ^ (rl & 7)) << 4) + ebc);
                float o = beta * acc[m][n2][r] + gamma * h2f(rb);
                o = fmaxf(o, 0.f);
                if (!LAST) {
                    if (row < M) hout[(size_t)row * 128 + col] = f2h(o);
                } else {
                    *(unsigned short*)
                        (Ah + rl * 256 + ((k8c ^ (rl & 7)) << 4) + ebc) = f2h(o);
                }
            }
        }
    }

    if (LAST) {
        __syncthreads();                       // Ah now holds h; Wh free
        for (int c = tid; c < 768; c += 256) { // 48 n-rows x 16 chunks
            int n = c >> 4, k8 = c & 15;
            *(short8*)(Wh + n * 256 + ((k8 ^ (n & 7)) << 4)) = *(const short8*)&Wot[n * 128 + k8 * 8];
        }
        __syncthreads();

        f32x4 oacc[3];
        #pragma unroll
        for (int n2 = 0; n2 < 3; ++n2) oacc[n2] = (f32x4){0.f, 0.f, 0.f, 0.f};

        #pragma unroll
        for (int kk = 0; kk < 4; ++kk) {
            int k8 = kk * 4 + lg;
            int row = w * 16 + lr;             // wave w -> rows w*16..+15
            half8 a = *(const half8*)(Ah + row * 256 + ((k8 ^ (row & 7)) << 4));
            #pragma unroll
            for (int n2 = 0; n2 < 3; ++n2) {
                int n = n2 * 16 + lr;
                half8 b = *(const half8*)(Wh + n * 256 + ((k8 ^ (n & 7)) << 4));
                oacc[n2] = __builtin_amdgcn_mfma_f32_16x16x32_f16(a, b, oacc[n2], 0, 0, 0);
            }
        }

        #pragma unroll
        for (int n2 = 0; n2 < 3; ++n2) {
            int col = n2 * 16 + lr;
            if (col < C) {
                float bb = obias[col];
                #pragma unroll
                for (int r = 0; r < 4; ++r) {
                    int row = row0 + w * 16 + lg * 4 + r;
                    if (row < M) outf[(size_t)row * C + col] = oacc[n2][r] + bb;
                }
            }
        }
    }
}

// ---------------- host ----------------

extern "C" void kernel_launch(void* const* d_in, const int* in_sizes, int n_in,
                              void* d_out, int out_size, void* d_ws, size_t ws_size,
                              hipStream_t stream) {
    const float* x        = (const float*)d_in[0];
    const int*   ei       = (const int*)d_in[1];
    const float* W_in     = (const float*)d_in[2];
    const float* b_in     = (const float*)d_in[3];
    const float* W_layers = (const float*)d_in[4];
    const float* W_out    = (const float*)d_in[5];
    const float* b_out    = (const float*)d_in[6];
    float* out = (float*)d_out;

    const int H = 128;
    const int N = in_sizes[0] / H;             // 50000 (< 65536 for packed CSR)
    const int E = in_sizes[1] / 2;             // 800000
    const int L = in_sizes[4] / (H * H);       // 4
    const int C = in_sizes[5] / H;             // 40

    char* p = (char*)d_ws;
    auto alloc = [&](size_t bytes) {
        char* r = p;
        p += (bytes + 255) & ~(size_t)255;
        return r;
    };
    int*      cnt   = (int*)alloc((size_t)N * 4);
    int*      offs  = (int*)alloc((size_t)(N + 1) * 4);
    int*      parts = (int*)alloc(256 * 4);
    unsigned* csr   = (unsigned*)alloc((size_t)E * 4);
    unsigned short* rank = (unsigned short*)alloc((size_t)E * 2);
    float*    dinv  = (float*)alloc((size_t)N * 4);
    unsigned short* hb0  = (unsigned short*)alloc((size_t)N * H * 2);
    unsigned short* hb1  = (unsigned short*)alloc((size_t)N * H * 2);
    unsigned short* h0b  = (unsigned short*)alloc((size_t)N * H * 2);
    unsigned short* wt   = (unsigned short*)alloc((size_t)L * H * H * 2);
    unsigned short* wint = (unsigned short*)alloc((size_t)H * H * 2);
    unsigned short* wot  = (unsigned short*)alloc((size_t)48 * H * 2);
    (void)ws_size;

    const int* ei0 = ei;        // destinations (row)
    const int* ei1 = ei + E;    // sources (col)

    const int nblkN = (N + 255) / 256;
    const int nblkE = (E + 255) / 256;
    const int n16   = (N + 3) / 4;

    k_wprep<<<6, 256, 0, stream>>>(W_layers, W_in, W_out, wt, wint, wot, C);

    k_zero<<<(n16 + 255) / 256, 256, 0, stream>>>((uint4*)cnt, n16);
    k_count<<<nblkE, 256, 0, stream>>>(ei0, cnt, rank, E);
    k_scan_part<<<nblkN, 256, 0, stream>>>(cnt, offs, parts, dinv, N);
    k_scan_tops<<<1, 256, 0, stream>>>(parts, nblkN);
    k_scan_add<<<nblkN, 256, 0, stream>>>(offs, parts, N, E);
    k_scatter<<<nblkE, 256, 0, stream>>>(ei0, ei1, rank, offs, dinv, csr, E);

    // input linear + relu -> hb0, h0b (fp16)
    gemm_in<<<(N + 63) / 64, 256, 48 * 1024, stream>>>(x, wint, b_in, hb0, h0b, N);

    const int gblk = (N + 63) / 64;
    unsigned short* bufs[2] = {hb0, hb1};
    for (int l = 0; l < L; ++l) {
        float beta = logf(0.5f / (float)(l + 1) + 1.0f);
        unsigned short* hin  = bufs[l & 1];
        unsigned short* houtb = bufs[(l + 1) & 1];
        if (l < L - 1)
            k_layer<0><<<gblk, 256, 48 * 1024, stream>>>(
                offs, csr, hin, h0b, dinv, wt + (size_t)l * H * H,
                nullptr, nullptr, beta, 1.0f - beta, houtb, nullptr, N, C, E);
        else
            k_layer<1><<<gblk, 256, 48 * 1024, stream>>>(
                offs, csr, hin, h0b, dinv, wt + (size_t)l * H * H,
                wot, b_out, beta, 1.0f - beta, nullptr, out, N, C, E);
    }
}

// Round 14
// 281.525 us; speedup vs baseline: 1.2213x; 1.2213x over previous
//
#include <hip/hip_runtime.h>
#include <hip/hip_bf16.h>
#include <hip/hip_fp16.h>
#include <math.h>

typedef short short8 __attribute__((ext_vector_type(8)));
typedef _Float16 half8 __attribute__((ext_vector_type(8)));
typedef float f32x4  __attribute__((ext_vector_type(4)));

__device__ __forceinline__ unsigned short f2h(float f) {
    return __half_as_ushort(__float2half(f));
}
__device__ __forceinline__ float h2f(unsigned short u) {
    return __half2float(__ushort_as_half(u));
}

// ---------------- CSR build (rank-based, atomic-free scatter) -------------
// 4 edges per thread: 4 independent atomics in flight per lane before the
// single ushort4 rank store (amortizes fabric round-trip latency).

__global__ void k_count(const int* __restrict__ dst, int* __restrict__ cnt,
                        unsigned short* __restrict__ rank, int E) {
    int t = blockIdx.x * 256 + threadIdx.x;
    int e = t * 4;
    if (e + 3 < E) {
        int4 d = *(const int4*)&dst[e];
        unsigned r0 = atomicAdd(&cnt[d.x], 1);
        unsigned r1 = atomicAdd(&cnt[d.y], 1);
        unsigned r2 = atomicAdd(&cnt[d.z], 1);
        unsigned r3 = atomicAdd(&cnt[d.w], 1);
        *(ushort4*)&rank[e] = make_ushort4((unsigned short)r0, (unsigned short)r1,
                                           (unsigned short)r2, (unsigned short)r3);
    } else {
        for (; e < E; ++e)
            rank[e] = (unsigned short)atomicAdd(&cnt[dst[e]], 1);
    }
}

// scan over cnt -> block-local exclusive offs (+ dinv folded in)
__global__ void k_scan_part(const int* __restrict__ cnt, int* __restrict__ offs,
                            int* __restrict__ parts, float* __restrict__ dinv, int n) {
    __shared__ int s[256];
    int i = blockIdx.x * 256 + threadIdx.x;
    int v = (i < n) ? cnt[i] : 0;
    s[threadIdx.x] = v;
    __syncthreads();
    #pragma unroll
    for (int d = 1; d < 256; d <<= 1) {
        int t = (threadIdx.x >= d) ? s[threadIdx.x - d] : 0;
        __syncthreads();
        s[threadIdx.x] += t;
        __syncthreads();
    }
    if (i < n) {
        offs[i] = s[threadIdx.x] - v;
        dinv[i] = rsqrtf((float)v + 1.0f);   // +1 self-loop
    }
    if (threadIdx.x == 255) parts[blockIdx.x] = s[255];
}

__global__ void k_scan_tops(int* __restrict__ parts, int np) {
    __shared__ int s[256];
    int tid = threadIdx.x;
    int v = (tid < np) ? parts[tid] : 0;
    s[tid] = v;
    __syncthreads();
    #pragma unroll
    for (int d = 1; d < 256; d <<= 1) {
        int t = (tid >= d) ? s[tid - d] : 0;
        __syncthreads();
        s[tid] += t;
        __syncthreads();
    }
    if (tid < np) parts[tid] = s[tid] - v;          // exclusive
}

__global__ void k_scan_add(int* __restrict__ offs, const int* __restrict__ parts,
                           int n, int e_total) {
    int i = blockIdx.x * 256 + threadIdx.x;
    if (i < n) offs[i] += parts[blockIdx.x];
    if (blockIdx.x == 0 && threadIdx.x == 0) offs[n] = e_total;
}

// csr entry (4B) = fp16(0.9*dinv[d]*dinv[s]) << 16 | src  — atomic-free.
// 4 edges/thread: 12 independent random loads + 4 stores in flight.
__global__ void k_scatter(const int* __restrict__ dst, const int* __restrict__ src,
                          const unsigned short* __restrict__ rank,
                          const int* __restrict__ offs,
                          const float* __restrict__ dinv,
                          unsigned* __restrict__ csr, int E) {
    int t = blockIdx.x * 256 + threadIdx.x;
    int e = t * 4;
    if (e + 3 < E) {
        int4 d = *(const int4*)&dst[e];
        int4 s = *(const int4*)&src[e];
        ushort4 r = *(const ushort4*)&rank[e];
        float dd0 = dinv[d.x], dd1 = dinv[d.y], dd2 = dinv[d.z], dd3 = dinv[d.w];
        float ds0 = dinv[s.x], ds1 = dinv[s.y], ds2 = dinv[s.z], ds3 = dinv[s.w];
        int o0 = offs[d.x], o1 = offs[d.y], o2 = offs[d.z], o3 = offs[d.w];
        csr[o0 + r.x] = ((unsigned)f2h(0.9f * dd0 * ds0) << 16) | (unsigned)s.x;
        csr[o1 + r.y] = ((unsigned)f2h(0.9f * dd1 * ds1) << 16) | (unsigned)s.y;
        csr[o2 + r.z] = ((unsigned)f2h(0.9f * dd2 * ds2) << 16) | (unsigned)s.z;
        csr[o3 + r.w] = ((unsigned)f2h(0.9f * dd3 * ds3) << 16) | (unsigned)s.w;
    } else {
        for (; e < E; ++e) {
            int d = dst[e], s = src[e];
            float w = 0.9f * dinv[d] * dinv[s];
            csr[offs[d] + (int)rank[e]] = ((unsigned)f2h(w) << 16) | (unsigned)s;
        }
    }
}

// ---------------- weight prep (all fp16, transposed) + cnt zero ----------

__global__ void k_wprep(const float* __restrict__ Wl, const float* __restrict__ Win,
                        const float* __restrict__ Wout,
                        unsigned short* __restrict__ wt,
                        unsigned short* __restrict__ wint,
                        unsigned short* __restrict__ wot, int C,
                        uint4* __restrict__ cntz, int n16) {
    int m = blockIdx.x;
    if (m < 4) {
        for (int i = threadIdx.x; i < 16384; i += 256) {
            int n = i >> 7, k = i & 127;
            wt[m * 16384 + n * 128 + k] = f2h(Wl[m * 16384 + k * 128 + n]);
        }
    } else if (m == 4) {
        for (int i = threadIdx.x; i < 16384; i += 256) {
            int n = i >> 7, k = i & 127;
            wint[n * 128 + k] = f2h(Win[k * 128 + n]);
        }
    } else if (m == 5) {
        for (int i = threadIdx.x; i < 48 * 128; i += 256) {
            int n = i >> 7, k = i & 127;
            wot[n * 128 + k] = (n < C) ? f2h(Wout[k * C + n]) : (unsigned short)0;
        }
    } else {
        int i = (m - 6) * 256 + threadIdx.x;
        if (i < n16) cntz[i] = make_uint4(0u, 0u, 0u, 0u);
    }
}

// ---------------- SpMM: supb = fp16(0.9*A_hat*h + 0.1*h0) ----------------
// HALF-WAVE per node; lane owns 4 fp16 features (8B gather). 16/8/4/2/1
// gather tiers keep up to 16 loads in flight. 0 LDS, 24 VGPR -> max waves.

__global__ __launch_bounds__(256)
void k_spmm(const int* __restrict__ offs, const unsigned* __restrict__ csr,
            const unsigned short* __restrict__ hb,
            const unsigned short* __restrict__ h0b,
            const float* __restrict__ dinv,
            unsigned short* __restrict__ supb, int n, int E) {
    int node = blockIdx.x * 8 + (threadIdx.x >> 5);
    if (node >= n) return;
    int l32 = threadIdx.x & 31;
    float di = dinv[node];
    float ws = 0.9f * di * di;
    uint2 sv = *(const uint2*)&hb [((size_t)node << 7) + (l32 << 2)];
    uint2 rv = *(const uint2*)&h0b[((size_t)node << 7) + (l32 << 2)];
    float ax = ws * h2f((unsigned short)(sv.x & 0xffffu)) + 0.1f * h2f((unsigned short)(rv.x & 0xffffu));
    float ay = ws * h2f((unsigned short)(sv.x >> 16))     + 0.1f * h2f((unsigned short)(rv.x >> 16));
    float az = ws * h2f((unsigned short)(sv.y & 0xffffu)) + 0.1f * h2f((unsigned short)(rv.y & 0xffffu));
    float aw = ws * h2f((unsigned short)(sv.y >> 16))     + 0.1f * h2f((unsigned short)(rv.y >> 16));
    int e = offs[node], end = offs[node + 1];
    while (e < end) {
        int nb = end - e;
        if (nb > 32) nb = 32;
        unsigned ce = csr[min(e + l32, E - 1)];   // coalesced 128B per half
        int i = 0;
        for (; i + 16 <= nb; i += 16) {
            uint2 g[16]; float wv[16];
            #pragma unroll
            for (int j = 0; j < 16; ++j) {
                unsigned u = __shfl(ce, i + j, 32);
                wv[j] = h2f((unsigned short)(u >> 16));
                g[j] = *(const uint2*)&hb[((size_t)(u & 0xffffu) << 7) + (l32 << 2)];
            }
            #pragma unroll
            for (int j = 0; j < 16; ++j) {
                ax += wv[j] * h2f((unsigned short)(g[j].x & 0xffffu));
                ay += wv[j] * h2f((unsigned short)(g[j].x >> 16));
                az += wv[j] * h2f((unsigned short)(g[j].y & 0xffffu));
                aw += wv[j] * h2f((unsigned short)(g[j].y >> 16));
            }
        }
        for (; i + 8 <= nb; i += 8) {
            uint2 g[8]; float wv[8];
            #pragma unroll
            for (int j = 0; j < 8; ++j) {
                unsigned u = __shfl(ce, i + j, 32);
                wv[j] = h2f((unsigned short)(u >> 16));
                g[j] = *(const uint2*)&hb[((size_t)(u & 0xffffu) << 7) + (l32 << 2)];
            }
            #pragma unroll
            for (int j = 0; j < 8; ++j) {
                ax += wv[j] * h2f((unsigned short)(g[j].x & 0xffffu));
                ay += wv[j] * h2f((unsigned short)(g[j].x >> 16));
                az += wv[j] * h2f((unsigned short)(g[j].y & 0xffffu));
                aw += wv[j] * h2f((unsigned short)(g[j].y >> 16));
            }
        }
        for (; i + 4 <= nb; i += 4) {
            uint2 g[4]; float wv[4];
            #pragma unroll
            for (int j = 0; j < 4; ++j) {
                unsigned u = __shfl(ce, i + j, 32);
                wv[j] = h2f((unsigned short)(u >> 16));
                g[j] = *(const uint2*)&hb[((size_t)(u & 0xffffu) << 7) + (l32 << 2)];
            }
            #pragma unroll
            for (int j = 0; j < 4; ++j) {
                ax += wv[j] * h2f((unsigned short)(g[j].x & 0xffffu));
                ay += wv[j] * h2f((unsigned short)(g[j].x >> 16));
                az += wv[j] * h2f((unsigned short)(g[j].y & 0xffffu));
                aw += wv[j] * h2f((unsigned short)(g[j].y >> 16));
            }
        }
        for (; i + 2 <= nb; i += 2) {
            uint2 g[2]; float wv[2];
            #pragma unroll
            for (int j = 0; j < 2; ++j) {
                unsigned u = __shfl(ce, i + j, 32);
                wv[j] = h2f((unsigned short)(u >> 16));
                g[j] = *(const uint2*)&hb[((size_t)(u & 0xffffu) << 7) + (l32 << 2)];
            }
            #pragma unroll
            for (int j = 0; j < 2; ++j) {
                ax += wv[j] * h2f((unsigned short)(g[j].x & 0xffffu));
                ay += wv[j] * h2f((unsigned short)(g[j].x >> 16));
                az += wv[j] * h2f((unsigned short)(g[j].y & 0xffffu));
                aw += wv[j] * h2f((unsigned short)(g[j].y >> 16));
            }
        }
        for (; i < nb; ++i) {
            unsigned u = __shfl(ce, i, 32);
            float w = h2f((unsigned short)(u >> 16));
            uint2 g = *(const uint2*)&hb[((size_t)(u & 0xffffu) << 7) + (l32 << 2)];
            ax += w * h2f((unsigned short)(g.x & 0xffffu));
            ay += w * h2f((unsigned short)(g.x >> 16));
            az += w * h2f((unsigned short)(g.y & 0xffffu));
            aw += w * h2f((unsigned short)(g.y >> 16));
        }
        e += nb;
    }
    uint2 o;
    o.x = (unsigned)f2h(ax) | ((unsigned)f2h(ay) << 16);
    o.y = (unsigned)f2h(az) | ((unsigned)f2h(aw) << 16);
    *(uint2*)&supb[((size_t)node << 7) + (l32 << 2)] = o;
}

// ---------------- input GEMM: relu(x@W_in + b) -> hb, h0b (fp16) ----------

__global__ __launch_bounds__(256)
void gemm_in(const float* __restrict__ inA,
             const unsigned short* __restrict__ Bh,
             const float* __restrict__ bias,
             unsigned short* __restrict__ hb,
             unsigned short* __restrict__ h0b, int M) {
    extern __shared__ char lds[];
    char* Ah = lds;                  // 64*128 fp16 = 16KB
    char* Wh = Ah + 16384;           // 32KB

    const int tid  = threadIdx.x;
    const int row0 = blockIdx.x * 64;

    for (int c = tid; c < 1024; c += 256) {            // 64 rows x 16 chunks
        int row = c >> 4, k8 = c & 15;
        int grow = row0 + row;
        short8 hv = {0,0,0,0,0,0,0,0};
        if (grow < M) {
            const float* s = &inA[(size_t)grow * 128 + k8 * 8];
            float4 f0 = *(const float4*)s;
            float4 f1 = *(const float4*)(s + 4);
            float ff[8] = {f0.x, f0.y, f0.z, f0.w, f1.x, f1.y, f1.z, f1.w};
            #pragma unroll
            for (int j = 0; j < 8; ++j) hv[j] = (short)f2h(ff[j]);
        }
        *(short8*)(Ah + row * 256 + ((k8 ^ (row & 7)) << 4)) = hv;
    }
    for (int c = tid; c < 2048; c += 256) {
        int n = c >> 4, k8 = c & 15;
        *(short8*)(Wh + n * 256 + ((k8 ^ (n & 7)) << 4)) = *(const short8*)&Bh[n * 128 + k8 * 8];
    }
    __syncthreads();

    const int lane = tid & 63;
    const int w    = tid >> 6;
    const int lr   = lane & 15;
    const int lg   = lane >> 4;

    f32x4 acc[4][2];
    #pragma unroll
    for (int m = 0; m < 4; ++m)
        #pragma unroll
        for (int n2 = 0; n2 < 2; ++n2) acc[m][n2] = (f32x4){0.f, 0.f, 0.f, 0.f};

    #pragma unroll
    for (int kk = 0; kk < 4; ++kk) {
        int k8 = kk * 4 + lg;
        half8 a[4], b[2];
        #pragma unroll
        for (int m = 0; m < 4; ++m) {
            int row = m * 16 + lr;
            a[m] = *(const half8*)(Ah + row * 256 + ((k8 ^ (row & 7)) << 4));
        }
        #pragma unroll
        for (int n2 = 0; n2 < 2; ++n2) {
            int n = (w * 2 + n2) * 16 + lr;
            b[n2] = *(const half8*)(Wh + n * 256 + ((k8 ^ (n & 7)) << 4));
        }
        #pragma unroll
        for (int m = 0; m < 4; ++m)
            #pragma unroll
            for (int n2 = 0; n2 < 2; ++n2)
                acc[m][n2] = __builtin_amdgcn_mfma_f32_16x16x32_f16(a[m], b[n2], acc[m][n2], 0, 0, 0);
    }

    #pragma unroll
    for (int m = 0; m < 4; ++m) {
        #pragma unroll
        for (int n2 = 0; n2 < 2; ++n2) {
            int col = (w * 2 + n2) * 16 + lr;
            #pragma unroll
            for (int r = 0; r < 4; ++r) {
                int row = row0 + m * 16 + lg * 4 + r;
                if (row < M) {
                    float o = fmaxf(acc[m][n2][r] + bias[col], 0.f);
                    unsigned short ob = f2h(o);
                    hb [(size_t)row * 128 + col] = ob;
                    h0b[(size_t)row * 128 + col] = ob;
                }
            }
        }
    }
}

// ---------------- layer GEMM: relu(beta*(sup@W) + (1-beta)*sup) -----------
// 128-row tile, 512 threads (8 waves: 4 row-groups x 2 col-groups),
// 64KB LDS -> 2 blocks/CU. Residual from the staged LDS tile.

__global__ __launch_bounds__(512)
void gemm_layer(const unsigned short* __restrict__ supb,
                const unsigned short* __restrict__ Bh,
                float beta, float gamma,
                unsigned short* __restrict__ outh, int M) {
    extern __shared__ char lds[];
    char* Ah = lds;                  // 128 rows x 256B = 32KB
    char* Wh = Ah + 32768;           // 32KB

    const int tid  = threadIdx.x;
    const int row0 = blockIdx.x * 128;

    for (int c = tid; c < 2048; c += 512) {            // 128 rows x 16 chunks
        int row = c >> 4, k8 = c & 15;
        int grow = row0 + row;
        short8 hv = {0,0,0,0,0,0,0,0};
        if (grow < M) hv = *(const short8*)&supb[(size_t)grow * 128 + k8 * 8];
        *(short8*)(Ah + row * 256 + ((k8 ^ (row & 7)) << 4)) = hv;
    }
    for (int c = tid; c < 2048; c += 512) {
        int n = c >> 4, k8 = c & 15;
        *(short8*)(Wh + n * 256 + ((k8 ^ (n & 7)) << 4)) = *(const short8*)&Bh[n * 128 + k8 * 8];
    }
    __syncthreads();

    const int lane = tid & 63;
    const int w    = tid >> 6;        // 0..7
    const int wr   = w >> 1;          // row-group: rows wr*32..+31
    const int wc   = w & 1;           // col-group: cols wc*64..+63
    const int lr   = lane & 15;
    const int lg   = lane >> 4;

    f32x4 acc[2][4];
    #pragma unroll
    for (int m = 0; m < 2; ++m)
        #pragma unroll
        for (int n2 = 0; n2 < 4; ++n2) acc[m][n2] = (f32x4){0.f, 0.f, 0.f, 0.f};

    #pragma unroll
    for (int kk = 0; kk < 4; ++kk) {
        int k8 = kk * 4 + lg;
        half8 a[2], b[4];
        #pragma unroll
        for (int m = 0; m < 2; ++m) {
            int row = wr * 32 + m * 16 + lr;
            a[m] = *(const half8*)(Ah + row * 256 + ((k8 ^ (row & 7)) << 4));
        }
        #pragma unroll
        for (int n2 = 0; n2 < 4; ++n2) {
            int n = wc * 64 + n2 * 16 + lr;
            b[n2] = *(const half8*)(Wh + n * 256 + ((k8 ^ (n & 7)) << 4));
        }
        #pragma unroll
        for (int m = 0; m < 2; ++m)
            #pragma unroll
            for (int n2 = 0; n2 < 4; ++n2)
                acc[m][n2] = __builtin_amdgcn_mfma_f32_16x16x32_f16(a[m], b[n2], acc[m][n2], 0, 0, 0);
    }

    #pragma unroll
    for (int m = 0; m < 2; ++m) {
        #pragma unroll
        for (int n2 = 0; n2 < 4; ++n2) {
            int col = wc * 64 + n2 * 16 + lr;
            int k8c = col >> 3;
            int ebc = (col & 7) * 2;
            #pragma unroll
            for (int r = 0; r < 4; ++r) {
                int rl  = wr * 32 + m * 16 + lg * 4 + r;
                int row = row0 + rl;
                if (row < M) {
                    unsigned short rb = *(const unsigned short*)
                        (Ah + rl * 256 + ((k8c ^ (rl & 7)) << 4) + ebc);
                    float o = beta * acc[m][n2][r] + gamma * h2f(rb);
                    o = fmaxf(o, 0.f);
                    outh[(size_t)row * 128 + col] = f2h(o);
                }
            }
        }
    }
}

// ---------------- output GEMM (MFMA): [M,128]fp16 @ [128,48]fp16 + b ------

__global__ __launch_bounds__(256)
void k_out(const unsigned short* __restrict__ hb,
           const unsigned short* __restrict__ Wot,
           const float* __restrict__ bias,
           float* __restrict__ out, int M, int C) {
    extern __shared__ char lds[];
    char* Ah = lds;                  // 64*128 fp16 = 16KB
    char* Wh = Ah + 16384;           // 48*128 fp16 = 12KB

    const int tid  = threadIdx.x;
    const int row0 = blockIdx.x * 64;

    for (int c = tid; c < 1024; c += 256) {
        int row = c >> 4, k8 = c & 15;
        int grow = row0 + row;
        short8 hv = {0,0,0,0,0,0,0,0};
        if (grow < M) hv = *(const short8*)&hb[(size_t)grow * 128 + k8 * 8];
        *(short8*)(Ah + row * 256 + ((k8 ^ (row & 7)) << 4)) = hv;
    }
    for (int c = tid; c < 768; c += 256) {             // 48 rows x 16 chunks
        int n = c >> 4, k8 = c & 15;
        *(short8*)(Wh + n * 256 + ((k8 ^ (n & 7)) << 4)) = *(const short8*)&Wot[n * 128 + k8 * 8];
    }
    __syncthreads();

    const int lane = tid & 63;
    const int w    = tid >> 6;        // wave w -> rows w*16..w*16+15
    const int lr   = lane & 15;
    const int lg   = lane >> 4;

    f32x4 acc[3];
    #pragma unroll
    for (int n2 = 0; n2 < 3; ++n2) acc[n2] = (f32x4){0.f, 0.f, 0.f, 0.f};

    #pragma unroll
    for (int kk = 0; kk < 4; ++kk) {
        int k8 = kk * 4 + lg;
        int row = w * 16 + lr;
        half8 a = *(const half8*)(Ah + row * 256 + ((k8 ^ (row & 7)) << 4));
        #pragma unroll
        for (int n2 = 0; n2 < 3; ++n2) {
            int n = n2 * 16 + lr;
            half8 b = *(const half8*)(Wh + n * 256 + ((k8 ^ (n & 7)) << 4));
            acc[n2] = __builtin_amdgcn_mfma_f32_16x16x32_f16(a, b, acc[n2], 0, 0, 0);
        }
    }

    #pragma unroll
    for (int n2 = 0; n2 < 3; ++n2) {
        int col = n2 * 16 + lr;
        if (col < C) {
            float bb = bias[col];
            #pragma unroll
            for (int r = 0; r < 4; ++r) {
                int row = row0 + w * 16 + lg * 4 + r;
                if (row < M) out[(size_t)row * C + col] = acc[n2][r] + bb;
            }
        }
    }
}

// ---------------- host ----------------

extern "C" void kernel_launch(void* const* d_in, const int* in_sizes, int n_in,
                              void* d_out, int out_size, void* d_ws, size_t ws_size,
                              hipStream_t stream) {
    const float* x        = (const float*)d_in[0];
    const int*   ei       = (const int*)d_in[1];
    const float* W_in     = (const float*)d_in[2];
    const float* b_in     = (const float*)d_in[3];
    const float* W_layers = (const float*)d_in[4];
    const float* W_out    = (const float*)d_in[5];
    const float* b_out    = (const float*)d_in[6];
    float* out = (float*)d_out;

    const int H = 128;
    const int N = in_sizes[0] / H;             // 50000 (< 65536 for packed CSR)
    const int E = in_sizes[1] / 2;             // 800000
    const int L = in_sizes[4] / (H * H);       // 4
    const int C = in_sizes[5] / H;             // 40

    char* p = (char*)d_ws;
    auto alloc = [&](size_t bytes) {
        char* r = p;
        p += (bytes + 255) & ~(size_t)255;
        return r;
    };
    int*      cnt   = (int*)alloc((size_t)N * 4);
    int*      offs  = (int*)alloc((size_t)(N + 1) * 4);
    int*      parts = (int*)alloc(256 * 4);
    unsigned* csr   = (unsigned*)alloc((size_t)E * 4);
    unsigned short* rank = (unsigned short*)alloc((size_t)E * 2);
    float*    dinv  = (float*)alloc((size_t)N * 4);
    unsigned short* hb   = (unsigned short*)alloc((size_t)N * H * 2);
    unsigned short* h0b  = (unsigned short*)alloc((size_t)N * H * 2);
    unsigned short* supb = (unsigned short*)alloc((size_t)N * H * 2);
    unsigned short* wt   = (unsigned short*)alloc((size_t)L * H * H * 2);
    unsigned short* wint = (unsigned short*)alloc((size_t)H * H * 2);
    unsigned short* wot  = (unsigned short*)alloc((size_t)48 * H * 2);
    (void)ws_size;

    const int* ei0 = ei;        // destinations (row)
    const int* ei1 = ei + E;    // sources (col)

    const int nblkN  = (N + 255) / 256;
    const int nblkE4 = ((E + 3) / 4 + 255) / 256;
    const int n16    = (N + 3) / 4;
    const int zblk   = (n16 + 255) / 256;

    // weights prep + cnt zero in one launch (blocks 0..5 = weights, 6.. = zero)
    k_wprep<<<6 + zblk, 256, 0, stream>>>(W_layers, W_in, W_out, wt, wint, wot, C,
                                          (uint4*)cnt, n16);

    k_count<<<nblkE4, 256, 0, stream>>>(ei0, cnt, rank, E);
    k_scan_part<<<nblkN, 256, 0, stream>>>(cnt, offs, parts, dinv, N);
    k_scan_tops<<<1, 256, 0, stream>>>(parts, nblkN);
    k_scan_add<<<nblkN, 256, 0, stream>>>(offs, parts, N, E);
    k_scatter<<<nblkE4, 256, 0, stream>>>(ei0, ei1, rank, offs, dinv, csr, E);

    // input linear + relu -> hb, h0b (fp16)
    gemm_in<<<(N + 63) / 64, 256, 48 * 1024, stream>>>(x, wint, b_in, hb, h0b, N);

    for (int l = 0; l < L; ++l) {
        float beta = logf(0.5f / (float)(l + 1) + 1.0f);
        k_spmm<<<(N + 7) / 8, 256, 0, stream>>>(offs, csr, hb, h0b, dinv, supb, N, E);
        gemm_layer<<<(N + 127) / 128, 512, 64 * 1024, stream>>>(
            supb, wt + (size_t)l * H * H, beta, 1.0f - beta, hb, N);
    }

    k_out<<<(N + 63) / 64, 256, 28 * 1024, stream>>>(hb, wot, b_out, out, N, C);
}